// Round 10
// baseline (155.485 us; speedup 1.0000x reference)
//
#include <hip/hip_runtime.h>
#include <math.h>

// Problem constants
#define V    4
#define T    4
#define NSRC 100000   // NS
#define NHX  12288    // NH
#define E    100000
#define H    64
#define VT   16       // (v,t') edge types

#define SL    16           // dst-sort slices per vt
#define SLE   (E/SL)       // 6250 edges per slice
#define RCH   2            // src ranges for deg_out hist (u8 packed)
#define RBINS (NSRC/RCH)   // 50000 u8 bins -> 12500 words (50 KB LDS)
#define RW    (RBINS/4)
#define HF    8            // edge slices for deg_out hist
#define HE    (E/HF)       // 12500
#define NW    (NSRC/4)     // 25000 packed words per vt in cnt_part
#define NCH   12           // 1024-wide d-chunks per vt (NHX = 12*1024)
#define NPB   8            // nodes per epilogue block

// S1 sub-grid offsets
#define S1_TRANS  391                      // ceil(V*NSRC/1024)
#define S1_CNT    (RCH*HF*VT)              // 256
#define S1_DHIST  (SL*VT)                  // 256
// S2 sub-grid
#define S2_SCAN   (NCH*VT)                 // 192
#define S2_NSFIN  391                      // ceil(VT*NW/1024)

typedef float vf4 __attribute__((ext_vector_type(4)));

// ---------------------------------------------------------------------------
// S1: fused input-only stage (proven R8 structure).
//  [0,391): transpose x[v][t][s] -> x4[v][s] (nan_to_num folded)
//  [391,647): deg_out partial hist, u8 quads in u32 LDS words -> cnt_part
//  [647,903): per-(vt,slice) dst hist -> ph16 (u16) + chunk sums cs
// ---------------------------------------------------------------------------
__global__ void __launch_bounds__(1024)
s1_kernel(const float* __restrict__ x, const int* __restrict__ src,
          const int* __restrict__ dst, float4* __restrict__ x4,
          unsigned int* __restrict__ cnt_part, unsigned short* __restrict__ ph16,
          unsigned int* __restrict__ cs) {
    __shared__ unsigned int lds[RW];               // 50 KB (union for both branches)
    const int b = blockIdx.x, tid = threadIdx.x;

    if (b < S1_TRANS) {                            // ---- transpose ----
        const int g = b * 1024 + tid;
        if (g < V * NSRC) {
            const int v = g / NSRC, s = g - v * NSRC;
            const float* xr = x + (size_t)v * T * NSRC + s;
            float a0 = xr[0], a1 = xr[NSRC], a2 = xr[2 * NSRC], a3 = xr[3 * NSRC];
            float4 r;
            r.x = (a0 == a0) ? a0 : 0.0f;
            r.y = (a1 == a1) ? a1 : 0.0f;
            r.z = (a2 == a2) ? a2 : 0.0f;
            r.w = (a3 == a3) ? a3 : 0.0f;
            x4[g] = r;
        }
        return;
    }
    if (b < S1_TRANS + S1_CNT) {                   // ---- deg_out hist ----
        const int idx = b - S1_TRANS;
        const int rg = idx & 1;
        const int hf = (idx >> 1) & 7;
        const int vt = idx >> 4;
        const int lo = rg * RBINS;
        for (int i = tid; i < RW; i += 1024) lds[i] = 0u;
        __syncthreads();
        const int* s_row = src + vt * E + hf * HE;
        for (int e = tid; e < HE; e += 1024) {
            const unsigned r = (unsigned)(s_row[e] - lo);
            if (r < RBINS) atomicAdd(&lds[r >> 2], 1u << ((r & 3) * 8));
        }
        __syncthreads();
        unsigned int* outp = cnt_part + ((size_t)hf * VT + vt) * NW + rg * RW;
        for (int i = tid; i < RW; i += 1024) outp[i] = lds[i];
        return;
    }
    {                                              // ---- dst hist ----
        const int idx = b - (S1_TRANS + S1_CNT);
        const int sl = idx & 15, vt = idx >> 4;
        for (int i = tid; i < NHX; i += 1024) lds[i] = 0u;
        __syncthreads();
        const int* d_row = dst + vt * E + sl * SLE;
        for (int e = tid; e < SLE; e += 1024)
            atomicAdd(&lds[d_row[e]], 1u);
        __syncthreads();
        unsigned short* outp = ph16 + ((size_t)vt * SL + sl) * NHX;
        for (int i = tid; i < NHX; i += 1024)
            outp[i] = (unsigned short)lds[i];
        // non-atomic per-chunk totals: wave wv sums chunk wv
        const int lane = tid & 63, wv = tid >> 6;
        if (wv < NCH) {
            unsigned int s = 0;
#pragma unroll
            for (int i = 0; i < 16; ++i) s += lds[wv * 1024 + i * 64 + lane];
#pragma unroll
            for (int off = 32; off > 0; off >>= 1)
                s += (unsigned int)__shfl_down((int)s, off, 64);
            if (lane == 0) cs[((size_t)vt * SL + sl) * NCH + wv] = s;
        }
    }
}

// ---------------------------------------------------------------------------
// S2: fused CSR scan + nsfin (proven R8 structure — scan done ONCE per chunk).
//  [0,192): chunk (ch,vt) scan -> colstart/degs/start (base from cs sums)
//  [192,583): ns[vt][s] = rsqrt(max(deg_out,1)) from u8 partials
// ---------------------------------------------------------------------------
__global__ void __launch_bounds__(1024)
s2_kernel(const unsigned int* __restrict__ cnt_part,
          const unsigned short* __restrict__ ph16,
          const unsigned int* __restrict__ cs,
          float4* __restrict__ ns4,
          unsigned int* __restrict__ start,
          unsigned int* __restrict__ colstart,
          unsigned int* __restrict__ degs) {
    const int b = blockIdx.x, tid = threadIdx.x;

    if (b < S2_SCAN) {                             // ---- scan ----
        const int vt = b & 15, ch = b >> 4;
        const int lane = tid & 63, wv = tid >> 6;
        const int d = ch * 1024 + tid;
        __shared__ unsigned int wsum[16];
        __shared__ unsigned int sbase;
        // parallel chunk base: lane l (<16) sums slice l over chunks < ch
        if (wv == 0) {
            unsigned int p = 0;
            if (lane < SL)
                for (int c = 0; c < ch; ++c)
                    p += cs[((size_t)vt * SL + lane) * NCH + c];
#pragma unroll
            for (int off = 8; off > 0; off >>= 1)
                p += (unsigned int)__shfl_down((int)p, off, 64);
            if (lane == 0) sbase = p;
        }
        unsigned int h[SL];
        unsigned int tot = 0;
#pragma unroll
        for (int s = 0; s < SL; ++s) {
            h[s] = ph16[((size_t)vt * SL + s) * NHX + d];
            tot += h[s];
        }
        unsigned int incl = tot;
#pragma unroll
        for (int off = 1; off < 64; off <<= 1) {
            const unsigned int vup = (unsigned int)__shfl_up((int)incl, off, 64);
            if (lane >= off) incl += vup;
        }
        if (lane == 63) wsum[wv] = incl;
        __syncthreads();
        if (tid == 0) {
            unsigned int run = sbase;
#pragma unroll
            for (int w = 0; w < 16; ++w) { const unsigned int t2 = wsum[w]; wsum[w] = run; run += t2; }
        }
        __syncthreads();
        const unsigned int excl = wsum[wv] + (incl - tot);
        const size_t vd = (size_t)vt * NHX + d;
        colstart[vd] = excl;
        degs[vd]     = tot;
        unsigned int acc = excl;
#pragma unroll
        for (int s = 0; s < SL; ++s) {
            start[((size_t)vt * SL + s) * NHX + d] = acc;
            acc += h[s];
        }
        return;
    }
    {                                              // ---- nsfin ----
        const int g = (b - S2_SCAN) * 1024 + tid;  // word index (vt*NW+w)
        if (g >= VT * NW) return;
        unsigned c0 = 0, c1 = 0, c2 = 0, c3 = 0;
#pragma unroll
        for (int hf = 0; hf < HF; ++hf) {
            const unsigned w = cnt_part[(size_t)hf * VT * NW + g];
            c0 += w & 0xFFu; c1 += (w >> 8) & 0xFFu;
            c2 += (w >> 16) & 0xFFu; c3 += w >> 24;
        }
        float4 r;
        r.x = rsqrtf(fmaxf((float)c0, 1.0f));
        r.y = rsqrtf(fmaxf((float)c1, 1.0f));
        r.z = rsqrtf(fmaxf((float)c2, 1.0f));
        r.w = rsqrtf(fmaxf((float)c3, 1.0f));
        ns4[g] = r;
    }
}

// ---------------------------------------------------------------------------
// S3: reorder + gather-scale. For each edge: p = pos[d]++ (LDS cursor from
// start[]), then xs[p] = x4[v][s] * ns[vt][s]  (float4, pre-scaled VALUE —
// not the index). XCD swizzle (XCD k owns vt={2k,2k+1}) keeps x4/ns rows and
// the 1.6 MB/vt xs region L2-resident. Downstream reads become contiguous.
// ---------------------------------------------------------------------------
__global__ void __launch_bounds__(1024)
s3_reorder(const int* __restrict__ src, const int* __restrict__ dst,
           const unsigned int* __restrict__ start,
           const float4* __restrict__ x4, const float* __restrict__ ns,
           float4* __restrict__ xs) {
    const int b = blockIdx.x;              // 256 = 8 XCD * 2 vt * 16 sl
    const int k = b & 7, j = b >> 3;
    const int vt = 2 * k + (j & 1);
    const int sl = j >> 1;
    const int v = vt >> 2;
    __shared__ unsigned int pos[NHX];      // 48 KB
    const unsigned int* st = start + ((size_t)vt * SL + sl) * NHX;
    for (int i = threadIdx.x; i < NHX; i += 1024) pos[i] = st[i];
    __syncthreads();
    const int* s_row = src + vt * E + sl * SLE;
    const int* d_row = dst + vt * E + sl * SLE;
    const float*  ns_row = ns + (size_t)vt * NSRC;
    const float4* x_row  = x4 + (size_t)v * NSRC;
    float4* xs_row = xs + (size_t)vt * E;
    for (int e = threadIdx.x; e < SLE; e += 1024) {
        const int d = d_row[e];
        const int s = s_row[e];
        const unsigned int p = atomicAdd(&pos[d], 1u);
        const float4 xv = x_row[s];
        const float  nv = ns_row[s];
        float4 r;
        r.x = xv.x * nv; r.y = xv.y * nv;
        r.z = xv.z * nv; r.w = xv.w * nv;
        xs_row[p] = r;
    }
}

// ---------------------------------------------------------------------------
// S45: fused segmented-sum + epilogue. Block handles NPB=8 nodes:
//  phase 1: 2 threads per (vt,n) segment stream the CONTIGUOUS xs range
//           [colstart, colstart+deg), shfl-combine, normalize -> sv in LDS.
//  phase 2: verified epilogue math, nontemporal float4 out stores.
// ---------------------------------------------------------------------------
__global__ void __launch_bounds__(256)
s45_kernel(const float4* __restrict__ xs,
           const unsigned int* __restrict__ colstart,
           const unsigned int* __restrict__ degs,
           const float* __restrict__ Wm, const float* __restrict__ bm,
           float* __restrict__ out) {
    const int n0  = blockIdx.x * NPB;
    const int tid = threadIdx.x;
    __shared__ float sW[VT * H];
    __shared__ float sb[VT * H];
    __shared__ float sv[VT][T][NPB];

    for (int i = tid; i < VT * H; i += 256) { sW[i] = Wm[i]; sb[i] = bm[i]; }

    // ---- segment sums: 128 segments, 2 threads each ----
    {
        const int seg  = tid >> 1;         // 0..127 = vt*8 + n
        const int half = tid & 1;
        const int vt = seg >> 3, n = seg & 7;
        const size_t vd = (size_t)vt * NHX + (n0 + n);
        const unsigned int base = colstart[vd];
        const unsigned int deg  = degs[vd];
        const float4* xrow = xs + (size_t)vt * E;
        float4 acc = make_float4(0.f, 0.f, 0.f, 0.f);
        for (unsigned int i = half; i < deg; i += 2) {
            const float4 a = xrow[base + i];
            acc.x += a.x; acc.y += a.y; acc.z += a.z; acc.w += a.w;
        }
        acc.x += __shfl_xor(acc.x, 1, 64);
        acc.y += __shfl_xor(acc.y, 1, 64);
        acc.z += __shfl_xor(acc.z, 1, 64);
        acc.w += __shfl_xor(acc.w, 1, 64);
        if (half == 0) {
            const float nd = rsqrtf(fmaxf((float)deg, 1.0f));
            sv[vt][0][n] = acc.x * nd; sv[vt][1][n] = acc.y * nd;
            sv[vt][2][n] = acc.z * nd; sv[vt][3][n] = acc.w * nd;
        }
    }
    __syncthreads();

    // ---- epilogue ----
    const int v  = tid >> 6;
    const int t  = (tid >> 4) & 3;
    const int hb = (tid & 15) * 4;
    float4 Wr[4], Br[4];
#pragma unroll
    for (int tp = 0; tp < 4; ++tp) {
        const int wi = (v * 4 + tp) * H + hb;
        Wr[tp] = *(const float4*)&sW[wi];
        Br[tp] = *(const float4*)&sb[wi];
    }
#pragma unroll
    for (int n = 0; n < NPB; ++n) {
        float4 o = make_float4(0.f, 0.f, 0.f, 0.f);
#pragma unroll
        for (int tp = 0; tp < 4; ++tp) {
            const float s = sv[v * 4 + tp][t][n];
            float a;
            a = fmaf(s, Wr[tp].x, Br[tp].x); o.x += (a > 0.f) ? a : 0.01f * a;
            a = fmaf(s, Wr[tp].y, Br[tp].y); o.y += (a > 0.f) ? a : 0.01f * a;
            a = fmaf(s, Wr[tp].z, Br[tp].z); o.z += (a > 0.f) ? a : 0.01f * a;
            a = fmaf(s, Wr[tp].w, Br[tp].w); o.w += (a > 0.f) ? a : 0.01f * a;
        }
        vf4* dstp = (vf4*)(out + (size_t)(n0 + n) * (V * T * H)) + tid;
        __builtin_nontemporal_store(*(vf4*)&o, dstp);
    }
}

// ---------------------------------------------------------------------------
extern "C" void kernel_launch(void* const* d_in, const int* in_sizes, int n_in,
                              void* d_out, int out_size, void* d_ws, size_t ws_size,
                              hipStream_t stream) {
    const float* x   = (const float*)d_in[0];   // [V,T,NS]
    const float* Wm  = (const float*)d_in[1];   // [V,T,H]
    const float* bm  = (const float*)d_in[2];   // [V,T,H]
    const int*   src = (const int*)d_in[3];     // [V,T,E]
    const int*   dst = (const int*)d_in[4];     // [V,T,E]
    float* out = (float*)d_out;                 // [NH,V,T,H]

    // workspace ~72 MB; every region fully written before read -> no memset.
    // All region sizes multiples of 16 B.
    char* ws = (char*)d_ws;
    size_t off = 0;
    float4* x4 = (float4*)(ws + off);                   off += (size_t)V * NSRC * 16;        // 6.40 MB
    float4* ns4 = (float4*)(ws + off);                  off += (size_t)VT * NSRC * 4;        // 6.40 MB
    unsigned short* ph16 = (unsigned short*)(ws + off); off += (size_t)VT * SL * NHX * 2;    // 6.29 MB
    unsigned int* start = (unsigned int*)(ws + off);    off += (size_t)VT * SL * NHX * 4;    // 12.58 MB
    unsigned int* colstart = (unsigned int*)(ws + off); off += (size_t)VT * NHX * 4;         // 0.79 MB
    unsigned int* degs = (unsigned int*)(ws + off);     off += (size_t)VT * NHX * 4;         // 0.79 MB
    unsigned int* cs = (unsigned int*)(ws + off);       off += (size_t)VT * SL * NCH * 4;    // 12 KB
    unsigned int* cnt_part = (unsigned int*)(ws + off); off += (size_t)HF * VT * NW * 4;     // 12.80 MB
    float4* xs = (float4*)(ws + off);                   off += (size_t)VT * E * 16;          // 25.60 MB
    float* ns = (float*)ns4;

    s1_kernel<<<S1_TRANS + S1_CNT + S1_DHIST, 1024, 0, stream>>>(
        x, src, dst, x4, cnt_part, ph16, cs);
    s2_kernel<<<S2_SCAN + S2_NSFIN, 1024, 0, stream>>>(
        cnt_part, ph16, cs, ns4, start, colstart, degs);
    s3_reorder<<<SL * VT, 1024, 0, stream>>>(src, dst, start, x4, ns, xs);
    s45_kernel<<<NHX / NPB, 256, 0, stream>>>(xs, colstart, degs, Wm, bm, out);
}

// Round 11
// 142.047 us; speedup vs baseline: 1.0946x; 1.0946x over previous
//
#include <hip/hip_runtime.h>
#include <math.h>

// Problem constants
#define V    4
#define T    4
#define NSRC 100000   // NS
#define NHX  12288    // NH
#define E    100000
#define H    64
#define VT   16       // (v,t') edge types

#define SL    16           // dst-sort slices per vt
#define SLE   (E/SL)       // 6250 edges per slice
#define RCH   2            // src ranges for deg_out hist (u8 packed)
#define RBINS (NSRC/RCH)   // 50000 u8 bins -> 12500 words (50 KB LDS)
#define RW    (RBINS/4)
#define HF    8            // edge slices for deg_out hist
#define HE    (E/HF)       // 12500
#define NW    (NSRC/4)     // 25000 packed words per vt in cnt_part
#define NCH   12           // 1024-wide d-chunks per vt (NHX = 12*1024)
#define NPB   8            // nodes per epilogue block

// S1 sub-grid offsets
#define S1_TRANS  391                      // ceil(V*NSRC/1024)
#define S1_CNT    (RCH*HF*VT)              // 256
#define S1_DHIST  (SL*VT)                  // 256
// S2 sub-grid
#define S2_SCAN   (NCH*VT)                 // 192
#define S2_NSFIN  391                      // ceil(VT*NW/1024)

typedef float vf4 __attribute__((ext_vector_type(4)));

// ---------------------------------------------------------------------------
// S1: fused input-only stage (R8 champion structure, unchanged).
//  [0,391): transpose x[v][t][s] -> x4[v][s] (nan_to_num folded)
//  [391,647): deg_out partial hist, u8 quads in u32 LDS words -> cnt_part
//  [647,903): per-(vt,slice) dst hist -> ph16 (u16) + chunk sums cs
// ---------------------------------------------------------------------------
__global__ void __launch_bounds__(1024)
s1_kernel(const float* __restrict__ x, const int* __restrict__ src,
          const int* __restrict__ dst, float4* __restrict__ x4,
          unsigned int* __restrict__ cnt_part, unsigned short* __restrict__ ph16,
          unsigned int* __restrict__ cs) {
    __shared__ unsigned int lds[RW];               // 50 KB (union for both branches)
    const int b = blockIdx.x, tid = threadIdx.x;

    if (b < S1_TRANS) {                            // ---- transpose ----
        const int g = b * 1024 + tid;
        if (g < V * NSRC) {
            const int v = g / NSRC, s = g - v * NSRC;
            const float* xr = x + (size_t)v * T * NSRC + s;
            float a0 = xr[0], a1 = xr[NSRC], a2 = xr[2 * NSRC], a3 = xr[3 * NSRC];
            float4 r;
            r.x = (a0 == a0) ? a0 : 0.0f;
            r.y = (a1 == a1) ? a1 : 0.0f;
            r.z = (a2 == a2) ? a2 : 0.0f;
            r.w = (a3 == a3) ? a3 : 0.0f;
            x4[g] = r;
        }
        return;
    }
    if (b < S1_TRANS + S1_CNT) {                   // ---- deg_out hist ----
        const int idx = b - S1_TRANS;
        const int rg = idx & 1;
        const int hf = (idx >> 1) & 7;
        const int vt = idx >> 4;
        const int lo = rg * RBINS;
        for (int i = tid; i < RW; i += 1024) lds[i] = 0u;
        __syncthreads();
        const int* s_row = src + vt * E + hf * HE;
        for (int e = tid; e < HE; e += 1024) {
            const unsigned r = (unsigned)(s_row[e] - lo);
            if (r < RBINS) atomicAdd(&lds[r >> 2], 1u << ((r & 3) * 8));
        }
        __syncthreads();
        unsigned int* outp = cnt_part + ((size_t)hf * VT + vt) * NW + rg * RW;
        for (int i = tid; i < RW; i += 1024) outp[i] = lds[i];
        return;
    }
    {                                              // ---- dst hist ----
        const int idx = b - (S1_TRANS + S1_CNT);
        const int sl = idx & 15, vt = idx >> 4;
        for (int i = tid; i < NHX; i += 1024) lds[i] = 0u;
        __syncthreads();
        const int* d_row = dst + vt * E + sl * SLE;
        for (int e = tid; e < SLE; e += 1024)
            atomicAdd(&lds[d_row[e]], 1u);
        __syncthreads();
        unsigned short* outp = ph16 + ((size_t)vt * SL + sl) * NHX;
        for (int i = tid; i < NHX; i += 1024)
            outp[i] = (unsigned short)lds[i];
        // non-atomic per-chunk totals: wave wv sums chunk wv
        const int lane = tid & 63, wv = tid >> 6;
        if (wv < NCH) {
            unsigned int s = 0;
#pragma unroll
            for (int i = 0; i < 16; ++i) s += lds[wv * 1024 + i * 64 + lane];
#pragma unroll
            for (int off = 32; off > 0; off >>= 1)
                s += (unsigned int)__shfl_down((int)s, off, 64);
            if (lane == 0) cs[((size_t)vt * SL + sl) * NCH + wv] = s;
        }
    }
}

// ---------------------------------------------------------------------------
// S2: fused CSR scan + nsfin (R8 structure; start[] u32 replaced by u8
// per-slice prefix pre8 — slice prefix <= max in-degree ~30 << 255).
//  [0,192): chunk (ch,vt) scan -> colstart/degs/pre8 (base from cs sums)
//  [192,583): ns[vt][s] = rsqrt(max(deg_out,1)) from u8 partials
// ---------------------------------------------------------------------------
__global__ void __launch_bounds__(1024)
s2_kernel(const unsigned int* __restrict__ cnt_part,
          const unsigned short* __restrict__ ph16,
          const unsigned int* __restrict__ cs,
          float4* __restrict__ ns4,
          unsigned char* __restrict__ pre8,
          unsigned int* __restrict__ colstart,
          unsigned int* __restrict__ degs) {
    const int b = blockIdx.x, tid = threadIdx.x;

    if (b < S2_SCAN) {                             // ---- scan ----
        const int vt = b & 15, ch = b >> 4;
        const int lane = tid & 63, wv = tid >> 6;
        const int d = ch * 1024 + tid;
        __shared__ unsigned int wsum[16];
        __shared__ unsigned int sbase;
        // parallel chunk base: lane l (<16) sums slice l over chunks < ch
        if (wv == 0) {
            unsigned int p = 0;
            if (lane < SL)
                for (int c = 0; c < ch; ++c)
                    p += cs[((size_t)vt * SL + lane) * NCH + c];
#pragma unroll
            for (int off = 8; off > 0; off >>= 1)
                p += (unsigned int)__shfl_down((int)p, off, 64);
            if (lane == 0) sbase = p;
        }
        unsigned int h[SL];
        unsigned int tot = 0;
#pragma unroll
        for (int s = 0; s < SL; ++s) {
            h[s] = ph16[((size_t)vt * SL + s) * NHX + d];
            tot += h[s];
        }
        unsigned int incl = tot;
#pragma unroll
        for (int off = 1; off < 64; off <<= 1) {
            const unsigned int vup = (unsigned int)__shfl_up((int)incl, off, 64);
            if (lane >= off) incl += vup;
        }
        if (lane == 63) wsum[wv] = incl;
        __syncthreads();
        if (tid == 0) {
            unsigned int run = sbase;
#pragma unroll
            for (int w = 0; w < 16; ++w) { const unsigned int t2 = wsum[w]; wsum[w] = run; run += t2; }
        }
        __syncthreads();
        const unsigned int excl = wsum[wv] + (incl - tot);
        const size_t vd = (size_t)vt * NHX + d;
        colstart[vd] = excl;
        degs[vd]     = tot;
        unsigned int acc = 0;
#pragma unroll
        for (int s = 0; s < SL; ++s) {
            pre8[((size_t)vt * SL + s) * NHX + d] = (unsigned char)acc;
            acc += h[s];
        }
        return;
    }
    {                                              // ---- nsfin ----
        const int g = (b - S2_SCAN) * 1024 + tid;  // word index (vt*NW+w)
        if (g >= VT * NW) return;
        unsigned c0 = 0, c1 = 0, c2 = 0, c3 = 0;
#pragma unroll
        for (int hf = 0; hf < HF; ++hf) {
            const unsigned w = cnt_part[(size_t)hf * VT * NW + g];
            c0 += w & 0xFFu; c1 += (w >> 8) & 0xFFu;
            c2 += (w >> 16) & 0xFFu; c3 += w >> 24;
        }
        float4 r;
        r.x = rsqrtf(fmaxf((float)c0, 1.0f));
        r.y = rsqrtf(fmaxf((float)c1, 1.0f));
        r.z = rsqrtf(fmaxf((float)c2, 1.0f));
        r.w = rsqrtf(fmaxf((float)c3, 1.0f));
        ns4[g] = r;
    }
}

// ---------------------------------------------------------------------------
// S3: reorder (counting-sort placement). 256 blocks, XCD swizzle: XCD k owns
// vt={2k,2k+1}; slice start = colstart[d] + pre8[sl][d].
// ---------------------------------------------------------------------------
__global__ void __launch_bounds__(1024)
s3_reorder(const int* __restrict__ src, const int* __restrict__ dst,
           const unsigned int* __restrict__ colstart,
           const unsigned char* __restrict__ pre8,
           int* __restrict__ sorted) {
    const int b = blockIdx.x;              // 256 = 8 XCD * 2 vt * 16 sl
    const int k = b & 7, j = b >> 3;
    const int vt = 2 * k + (j & 1);
    const int sl = j >> 1;
    __shared__ unsigned int pos[NHX];      // 48 KB
    const unsigned int*  cst = colstart + (size_t)vt * NHX;
    const unsigned char* pr  = pre8 + ((size_t)vt * SL + sl) * NHX;
    for (int i = threadIdx.x; i < NHX; i += 1024)
        pos[i] = cst[i] + (unsigned int)pr[i];
    __syncthreads();
    const int* s_row = src + vt * E + sl * SLE;
    const int* d_row = dst + vt * E + sl * SLE;
    int* outp = sorted + (size_t)vt * E;
    for (int e = threadIdx.x; e < SLE; e += 1024) {
        const int d = d_row[e];
        const int s = s_row[e];
        const unsigned int p = atomicAdd(&pos[d], 1u);
        outp[p] = s;
    }
}

// ---------------------------------------------------------------------------
// S4: atomic-free accumulation. TWO threads per (vt,d): interleaved segment
// halves, combined via shfl_xor. XCD swizzle keeps x4/ns/sorted rows in L2.
// ---------------------------------------------------------------------------
__global__ void __launch_bounds__(256)
s4_accum(const float4* __restrict__ x4, const int* __restrict__ sorted,
         const float* __restrict__ ns,
         const unsigned int* __restrict__ colstart,
         const unsigned int* __restrict__ degs,
         float4* __restrict__ sval) {
    const int b = blockIdx.x;              // 1536 = 8 XCD * 2 vt * 96 chunks
    const int k = b & 7, j = b >> 3;       // j 0..191
    const int vt = 2 * k + (j & 1);
    const int chunk = j >> 1;              // 0..95
    const int d = chunk * 128 + (threadIdx.x >> 1);
    const int half = threadIdx.x & 1;
    const int v = vt >> 2;
    const size_t vd = (size_t)vt * NHX + d;
    const unsigned int base = colstart[vd];
    const unsigned int deg  = degs[vd];
    const int*    srt    = sorted + (size_t)vt * E;
    const float*  ns_row = ns + (size_t)vt * NSRC;
    const float4* x_row  = x4 + (size_t)v * NSRC;
    float4 acc = make_float4(0.f, 0.f, 0.f, 0.f);
    for (unsigned int i = half; i < deg; i += 2) {
        const int s = srt[base + i];
        const float4 xa = x_row[s];
        const float  na = ns_row[s];
        acc.x += xa.x * na; acc.y += xa.y * na;
        acc.z += xa.z * na; acc.w += xa.w * na;
    }
    acc.x += __shfl_xor(acc.x, 1, 64);
    acc.y += __shfl_xor(acc.y, 1, 64);
    acc.z += __shfl_xor(acc.z, 1, 64);
    acc.w += __shfl_xor(acc.w, 1, 64);
    if (half == 0) {
        const float nd = rsqrtf(fmaxf((float)deg, 1.0f));
        acc.x *= nd; acc.y *= nd; acc.z *= nd; acc.w *= nd;
        sval[vd] = acc;
    }
}

// ---------------------------------------------------------------------------
// S5: epilogue (verified math). Block handles NPB=8 nodes; nontemporal out.
// ---------------------------------------------------------------------------
__global__ void __launch_bounds__(256)
s5_epilogue(const float4* __restrict__ sval, const float* __restrict__ Wm,
            const float* __restrict__ bm, float* __restrict__ out) {
    const int n0  = blockIdx.x * NPB;
    const int tid = threadIdx.x;
    __shared__ float sW[VT * H];
    __shared__ float sb[VT * H];
    __shared__ float sv[VT][T][NPB];

    for (int i = tid; i < VT * H; i += 256) { sW[i] = Wm[i]; sb[i] = bm[i]; }
    if (tid < VT * NPB) {
        const int vt = tid >> 3, n = tid & 7;
        const float4 r = sval[(size_t)vt * NHX + n0 + n];
        sv[vt][0][n] = r.x; sv[vt][1][n] = r.y;
        sv[vt][2][n] = r.z; sv[vt][3][n] = r.w;
    }
    __syncthreads();

    const int v  = tid >> 6;
    const int t  = (tid >> 4) & 3;
    const int hb = (tid & 15) * 4;
    float4 Wr[4], Br[4];
#pragma unroll
    for (int tp = 0; tp < 4; ++tp) {
        const int wi = (v * 4 + tp) * H + hb;
        Wr[tp] = *(const float4*)&sW[wi];
        Br[tp] = *(const float4*)&sb[wi];
    }
#pragma unroll
    for (int n = 0; n < NPB; ++n) {
        float4 o = make_float4(0.f, 0.f, 0.f, 0.f);
#pragma unroll
        for (int tp = 0; tp < 4; ++tp) {
            const float s = sv[v * 4 + tp][t][n];
            float a;
            a = fmaf(s, Wr[tp].x, Br[tp].x); o.x += (a > 0.f) ? a : 0.01f * a;
            a = fmaf(s, Wr[tp].y, Br[tp].y); o.y += (a > 0.f) ? a : 0.01f * a;
            a = fmaf(s, Wr[tp].z, Br[tp].z); o.z += (a > 0.f) ? a : 0.01f * a;
            a = fmaf(s, Wr[tp].w, Br[tp].w); o.w += (a > 0.f) ? a : 0.01f * a;
        }
        vf4* dstp = (vf4*)(out + (size_t)(n0 + n) * (V * T * H)) + tid;
        __builtin_nontemporal_store(*(vf4*)&o, dstp);
    }
}

// ---------------------------------------------------------------------------
extern "C" void kernel_launch(void* const* d_in, const int* in_sizes, int n_in,
                              void* d_out, int out_size, void* d_ws, size_t ws_size,
                              hipStream_t stream) {
    const float* x   = (const float*)d_in[0];   // [V,T,NS]
    const float* Wm  = (const float*)d_in[1];   // [V,T,H]
    const float* bm  = (const float*)d_in[2];   // [V,T,H]
    const int*   src = (const int*)d_in[3];     // [V,T,E]
    const int*   dst = (const int*)d_in[4];     // [V,T,E]
    float* out = (float*)d_out;                 // [NH,V,T,H]

    // workspace ~34 MB; every region fully written before read -> no memset.
    // All region offsets multiples of 16 B.
    char* ws = (char*)d_ws;
    size_t off = 0;
    float4* x4 = (float4*)(ws + off);                   off += (size_t)V * NSRC * 16;        // 6.40 MB
    float4* sval = (float4*)(ws + off);                 off += (size_t)VT * NHX * 16;        // 3.15 MB
    float4* ns4 = (float4*)(ws + off);                  off += (size_t)VT * NSRC * 4;        // 6.40 MB
    unsigned short* ph16 = (unsigned short*)(ws + off); off += (size_t)VT * SL * NHX * 2;    // 6.29 MB
    unsigned char* pre8 = (unsigned char*)(ws + off);   off += (size_t)VT * SL * NHX;        // 3.15 MB
    unsigned int* colstart = (unsigned int*)(ws + off); off += (size_t)VT * NHX * 4;         // 0.79 MB
    unsigned int* degs = (unsigned int*)(ws + off);     off += (size_t)VT * NHX * 4;         // 0.79 MB
    unsigned int* cs = (unsigned int*)(ws + off);       off += (size_t)VT * SL * NCH * 4;    // 12 KB
    unsigned int* cnt_part = (unsigned int*)(ws + off); off += (size_t)HF * VT * NW * 4;     // 12.80 MB
    int* sorted = (int*)(ws + off);                     off += (size_t)VT * E * 4;           // 6.40 MB
    float* ns = (float*)ns4;

    s1_kernel<<<S1_TRANS + S1_CNT + S1_DHIST, 1024, 0, stream>>>(
        x, src, dst, x4, cnt_part, ph16, cs);
    s2_kernel<<<S2_SCAN + S2_NSFIN, 1024, 0, stream>>>(
        cnt_part, ph16, cs, ns4, pre8, colstart, degs);
    s3_reorder<<<SL * VT, 1024, 0, stream>>>(src, dst, colstart, pre8, sorted);
    s4_accum<<<1536, 256, 0, stream>>>(x4, sorted, ns, colstart, degs, sval);
    s5_epilogue<<<NHX / NPB, 256, 0, stream>>>(sval, Wm, bm, out);
}